// Round 3
// baseline (109.943 us; speedup 1.0000x reference)
//
#include <hip/hip_runtime.h>
#include <hip/hip_bf16.h>

// LIF recurrence: v = tau*v + (1-tau)*x_t ; s = (v > vth) ; v -= s (vth=1, reset=0)
// B=64, T=256, U=1024 fp32. One thread per (b,u) chain; coalesced across u.
//
// R2 post-mortem: burst-16 pipeline got kernel ~48 -> ~26 us (~3.9 TB/s), but
// the burst/drain shape averages only ~half the nominal outstanding loads.
// R3: depth-32 ROTATING software pipeline, fine-grained — issue load(t+32)
// right before computing t, so vmcnt sits at ~32 outstanding continuously.
// 4 waves/CU x 64 lanes x 32 x 4B = 32 KB/CU in flight -> Little's law no
// longer binds even at full HBM latency. Stores stay non-temporal (streamed,
// never re-read; don't evict the LLC-warm input).
//
// Bit-exactness vs numpy fp32: non-fused __fmul_rn/__fadd_rn so the spike
// compare (v > 1.0f) sees identical rounding to the reference.

constexpr int kB = 64;
constexpr int kT = 256;
constexpr int kU = 1024;
constexpr int kD = 32;              // pipeline depth (outstanding loads/thread)

__global__ __launch_bounds__(256)
void lif_kernel(const float* __restrict__ x, float* __restrict__ out) {
    const int idx = blockIdx.x * blockDim.x + threadIdx.x;   // over B*U
    const int b = idx >> 10;              // / kU
    const int u = idx & (kU - 1);         // % kU

    const size_t base = (size_t)b * kT * kU + u;
    const float* __restrict__ xp = x + base;
    float* __restrict__ op = out + base;

    float buf[kD];
    // prologue: fill the pipe with the first kD loads
#pragma unroll
    for (int j = 0; j < kD; ++j)
        buf[j] = xp[(size_t)j * kU];

    float v = 0.0f;
    // steady state: for each t, first issue load(t+kD) into the slot we're
    // about to free, then compute t. Rotating index is compile-time constant
    // because both loops are fully unrolled (kD divides kT).
    for (int c = 0; c < kT / kD - 1; ++c) {
        const int t0 = c * kD;
#pragma unroll
        for (int j = 0; j < kD; ++j) {
            const float xt = buf[j];                          // load issued kD ago
            buf[j] = xp[(size_t)(t0 + kD + j) * kU];          // refill slot now
            const float a  = __fmul_rn(0.25f, v);
            const float cc = __fmul_rn(0.75f, xt);
            v = __fadd_rn(a, cc);
            const float s = (v > 1.0f) ? 1.0f : 0.0f;
            v = __fsub_rn(v, s);
            __builtin_nontemporal_store(s, &op[(size_t)(t0 + j) * kU]);
        }
    }
    // epilogue: drain the last kD elements
    const int t0 = kT - kD;
#pragma unroll
    for (int j = 0; j < kD; ++j) {
        const float a  = __fmul_rn(0.25f, v);
        const float cc = __fmul_rn(0.75f, buf[j]);
        v = __fadd_rn(a, cc);
        const float s = (v > 1.0f) ? 1.0f : 0.0f;
        v = __fsub_rn(v, s);
        __builtin_nontemporal_store(s, &op[(size_t)(t0 + j) * kU]);
    }
}

extern "C" void kernel_launch(void* const* d_in, const int* in_sizes, int n_in,
                              void* d_out, int out_size, void* d_ws, size_t ws_size,
                              hipStream_t stream) {
    const float* x = (const float*)d_in[0];
    float* out = (float*)d_out;

    const int nthreads = kB * kU;          // 65536 chains (fixed parallelism)
    const int block = 256;
    const int grid = nthreads / block;     // 256 blocks -> 1 block/CU, 4 waves/CU
    lif_kernel<<<grid, block, 0, stream>>>(x, out);
}